// Round 7
// baseline (916.458 us; speedup 1.0000x reference)
//
#include <hip/hip_runtime.h>
#include <hip/hip_bf16.h>

// LinearStateSpace via truncated convolution:
//   y_t = D u_t + sum_{d=1..112} (C A^{d-1} B) u_{t-d},  rho(A)=0.9 -> tail ~1e-3.
// Precompute: ONE persistent kernel (256 WGs, software grid barriers) running an
// 8-level bf16x2 (hi+lo, 3-term) GEMM chain. Dual chain X_s=A^(2^s), Y_s=(A^T)^(2^s)
// makes every GEMM row-major-in / row-major-out => no split-K slab, no pack pass.
// Main conv: 128x128-tile MFMA GEMM, sliding-window A, XOR-swizzled LDS,
// double-buffered with counted s_waitcnt vmcnt(8) (T3-min + T4).

#define NSTEPS 32768
#define LTRUNC 112
#define NDBLK  (LTRUNC + 1)
#define KTOT   (NDBLK * 128)     // 14464
#define SPLITK 4                 // conv split-K

typedef __attribute__((ext_vector_type(8))) short short8;
typedef __attribute__((ext_vector_type(4))) float f32x4;
typedef __hip_bfloat16 bf16;

// ---- ws layout (bf16-element offsets, all constexpr) ----
#define ME 1048576
#define O_AHR 0
#define O_ALR (1*ME)
#define O_AHC (2*ME)
#define O_ALC (3*ME)
#define O_XPH (4*ME)
#define O_XPL (5*ME)
#define O_XQH (6*ME)
#define O_XQL (7*ME)
#define O_YPH (8*ME)
#define O_YPL (9*ME)
#define O_YQH (10*ME)
#define O_YQL (11*ME)
#define O_GH  (12*ME)
#define O_GL  (14*ME)
#define O_RTH (16*ME)                   // 16777216, Rt = R^T rows, 896x1024
#define O_RTL (O_RTH + 917504)
#define O_KBT (O_RTL + 917504)          // 128 x KTOT
#define O_UBF (O_KBT + 128*KTOT)        // (LTRUNC+NSTEPS) x 128
#define WS_ELEMS ((size_t)O_UBF + (size_t)(LTRUNC + NSTEPS) * 128)
#define O_BAR_BYTES ((WS_ELEMS * 2 + 255) & ~(size_t)255)

__device__ __forceinline__ void gload16(const void* g, void* l) {
  __builtin_amdgcn_global_load_lds(
      (const __attribute__((address_space(1))) void*)g,
      (__attribute__((address_space(3))) void*)l, 16, 0, 0);
}

__device__ __forceinline__ void split1(float x, bf16& h, bf16& l) {
  h = __float2bfloat16(x);
  l = __float2bfloat16(x - __bfloat162float(h));
}

// ---------- f32 -> (hi,lo) bf16, row-major ----------
__global__ __launch_bounds__(256) void split_rm(const float* __restrict__ src,
                                                bf16* __restrict__ hi, bf16* __restrict__ lo) {
  const int i = (blockIdx.x * 256 + threadIdx.x) * 4;
  const float4 v = *reinterpret_cast<const float4*>(src + i);
  const float vv[4] = {v.x, v.y, v.z, v.w};
#pragma unroll
  for (int j = 0; j < 4; ++j) { bf16 h, l; split1(vv[j], h, l); hi[i + j] = h; lo[i + j] = l; }
}

// ---------- f32 (RxC) -> (hi,lo) bf16 transposed (CxR) ----------
__global__ __launch_bounds__(256) void split_cm(const float* __restrict__ src,
                                                bf16* __restrict__ hi, bf16* __restrict__ lo,
                                                int R, int C) {
  __shared__ float t[64][65];
  const int r0 = blockIdx.y << 6, c0 = blockIdx.x << 6;
  const int tid = threadIdx.x;
#pragma unroll
  for (int i = 0; i < 16; ++i) {
    const int e = i * 256 + tid, rl = e >> 6, cl = e & 63;
    t[rl][cl] = src[(size_t)(r0 + rl) * C + c0 + cl];
  }
  __syncthreads();
#pragma unroll
  for (int i = 0; i < 16; ++i) {
    const int e = i * 256 + tid, cl = e >> 6, rl = e & 63;
    bf16 h, l; split1(t[rl][cl], h, l);
    hi[(size_t)(c0 + cl) * R + r0 + rl] = h;
    lo[(size_t)(c0 + cl) * R + r0 + rl] = l;
  }
}

// ---------- input transpose: inp(128 x 32768) -> Ubf bf16 (LTRUNC+32768) x 128 ----------
__global__ __launch_bounds__(256) void ubuild(const float* __restrict__ inp, bf16* __restrict__ Ubf) {
  __shared__ float tile[64][65];
  const int t0 = blockIdx.x << 6, s0 = blockIdx.y << 6;
  const int tid = threadIdx.x;
#pragma unroll
  for (int i = 0; i < 16; ++i) {
    const int e = i * 256 + tid, sl = e >> 6, tl = e & 63;
    tile[sl][tl] = inp[(size_t)(s0 + sl) * NSTEPS + t0 + tl];
  }
  __syncthreads();
#pragma unroll
  for (int i = 0; i < 16; ++i) {
    const int e = i * 256 + tid, tl = e >> 6, sl = e & 63;
    Ubf[(size_t)(LTRUNC + t0 + tl) * 128 + s0 + sl] = __float2bfloat16(tile[sl][tl]);
  }
}

// ---------- Kbt d=0 block = bf16(D) ----------
__global__ __launch_bounds__(256) void dinit(const float* __restrict__ Dw, bf16* __restrict__ Kbt) {
  const int e = blockIdx.x * 256 + threadIdx.x;   // 16384
  const int r = e >> 7, s = e & 127;
  Kbt[(size_t)r * KTOT + s] = __float2bfloat16(Dw[e]);
}

// ---------- persistent chain mega-kernel ----------
// Every GEMM: C = (Ah+Al)(Bh+Bl), A rm MxK(1024), B "col-major" = rm rows of the
// transposed factor, K=1024, per-WG one full 128x128 tile, out = rm hi/lo or Kbt.
struct Job { int ah, al, bh, bl, oh, ol, mt, nt, dbase; };
__device__ const Job JOBS[25] = {
  // L1: X1=A^2 (B=Y0), Y1 (B=X0), G1 = G0*A (B=Y0)
  {O_AHR,O_ALR,O_AHC,O_ALC,O_XPH,O_XPL,8,8,-1},
  {O_AHC,O_ALC,O_AHR,O_ALR,O_YPH,O_YPL,8,8,-1},
  {O_GH, O_GL, O_AHC,O_ALC,O_GH+131072,O_GL+131072,1,8,-1},
  // L2: X2 (B=Y1), Y2 (B=X1), G2-3 (B=Y1)
  {O_XPH,O_XPL,O_YPH,O_YPL,O_XQH,O_XQL,8,8,-1},
  {O_YPH,O_YPL,O_XPH,O_XPL,O_YQH,O_YQL,8,8,-1},
  {O_GH, O_GL, O_YPH,O_YPL,O_GH+262144,O_GL+262144,2,8,-1},
  // L3: X3 (B=Y2), Y3 (B=X2), G4-7 (B=Y2)
  {O_XQH,O_XQL,O_YQH,O_YQL,O_XPH,O_XPL,8,8,-1},
  {O_YQH,O_YQL,O_XQH,O_XQL,O_YPH,O_YPL,8,8,-1},
  {O_GH, O_GL, O_YQH,O_YQL,O_GH+524288,O_GL+524288,4,8,-1},
  // L4: X4=A^16 (B=Y3), Y4 (B=X3), G8-15 (B=Y3)
  {O_XPH,O_XPL,O_YPH,O_YPL,O_XQH,O_XQL,8,8,-1},
  {O_YPH,O_YPL,O_XPH,O_XPL,O_YQH,O_YQL,8,8,-1},
  {O_GH, O_GL, O_YPH,O_YPL,O_GH+1048576,O_GL+1048576,8,8,-1},
  // L5: X5=A^32 (B=Y4), Y5 (B=X4), Rt1 = Rt0 * X4
  {O_XQH,O_XQL,O_YQH,O_YQL,O_XPH,O_XPL,8,8,-1},
  {O_YQH,O_YQL,O_XQH,O_XQL,O_YPH,O_YPL,8,8,-1},
  {O_RTH,O_RTL,O_XQH,O_XQL,O_RTH+131072,O_RTL+131072,1,8,-1},
  // L6: X6=A^64 (B=Y5), Rt2-3 = Rt0-1 * X5
  {O_XPH,O_XPL,O_YPH,O_YPL,O_XQH,O_XQL,8,8,-1},
  {O_RTH,O_RTL,O_XPH,O_XPL,O_RTH+262144,O_RTL+262144,2,8,-1},
  // L7: Rt4-6 = Rt0-2 * X6; K m=0..3 (B=Rt_m)
  {O_RTH,O_RTL,O_XQH,O_XQL,O_RTH+524288,O_RTL+524288,3,8,-1},
  {O_GH,O_GL,O_RTH,       O_RTL,       O_KBT,0,16,1, 1},
  {O_GH,O_GL,O_RTH+131072,O_RTL+131072,O_KBT,0,16,1,17},
  {O_GH,O_GL,O_RTH+262144,O_RTL+262144,O_KBT,0,16,1,33},
  {O_GH,O_GL,O_RTH+393216,O_RTL+393216,O_KBT,0,16,1,49},
  // L8: K m=4..6
  {O_GH,O_GL,O_RTH+524288,O_RTL+524288,O_KBT,0,16,1,65},
  {O_GH,O_GL,O_RTH+655360,O_RTL+655360,O_KBT,0,16,1,81},
  {O_GH,O_GL,O_RTH+786432,O_RTL+786432,O_KBT,0,16,1,97},
};
__device__ const int LVL[9] = {0,3,6,9,12,15,17,22,25};

__global__ __launch_bounds__(256) void chain_mega(bf16* __restrict__ ws, int* __restrict__ bar)
{
  __shared__ __align__(16) bf16 sAh[8192], sAl[8192], sBh[8192], sBl[8192];
  const int tid = threadIdx.x, lane = tid & 63, wave = tid >> 6;
  const int wm = wave & 1, wn = wave >> 1, l15 = lane & 15, lk = lane >> 4;
  const int srow = tid >> 3, sc8 = (tid & 7) << 3;
  const int g8 = (((tid & 7) ^ (srow & 7)) << 3);           // pre-swizzled source chunk
  const int ca0 = ((lk ^ (l15 & 7)) << 3);                  // swizzled read offs, kh=0
  const int ca1 = (((4 + lk) ^ (l15 & 7)) << 3);            // kh=1

  for (int lvl = 0; lvl < 8; ++lvl) {
    int idx = blockIdx.x;
    int j = LVL[lvl];
    const int je = LVL[lvl + 1];
    while (j < je && idx >= JOBS[j].mt * JOBS[j].nt) { idx -= JOBS[j].mt * JOBS[j].nt; ++j; }
    if (j < je) {
      const Job job = JOBS[j];
      const int my = idx / job.nt, nx = idx - my * job.nt;
      const int m0 = my << 7, n0 = nx << 7;
      const bf16* Ah = ws + job.ah; const bf16* Al = ws + job.al;
      const bf16* Bh = ws + job.bh; const bf16* Bl = ws + job.bl;
      f32x4 acc[4][4] = {};
      for (int k0 = 0; k0 < 1024; k0 += 64) {
        __syncthreads();
#pragma unroll
        for (int p = 0; p < 4; ++p) {
          const int row = (p << 5) + srow;
          const int loff = row * 64 + sc8;
          const size_t aoff = (size_t)(m0 + row) * 1024 + k0 + g8;
          const size_t boff = (size_t)(n0 + row) * 1024 + k0 + g8;
          gload16(Ah + aoff, sAh + loff);
          gload16(Al + aoff, sAl + loff);
          gload16(Bh + boff, sBh + loff);
          gload16(Bl + boff, sBl + loff);
        }
        __syncthreads();
#pragma unroll
        for (int kh = 0; kh < 2; ++kh) {
          const int cb = kh ? ca1 : ca0;
          short8 ah[4], al[4], bh[4], bl[4];
#pragma unroll
          for (int mi = 0; mi < 4; ++mi) {
            const int r = ((wm << 6) + (mi << 4) + l15) * 64 + cb;
            ah[mi] = *reinterpret_cast<const short8*>(sAh + r);
            al[mi] = *reinterpret_cast<const short8*>(sAl + r);
          }
#pragma unroll
          for (int ni = 0; ni < 4; ++ni) {
            const int r = ((wn << 6) + (ni << 4) + l15) * 64 + cb;
            bh[ni] = *reinterpret_cast<const short8*>(sBh + r);
            bl[ni] = *reinterpret_cast<const short8*>(sBl + r);
          }
#pragma unroll
          for (int mi = 0; mi < 4; ++mi)
#pragma unroll
            for (int ni = 0; ni < 4; ++ni) {
              acc[mi][ni] = __builtin_amdgcn_mfma_f32_16x16x32_bf16(ah[mi], bh[ni], acc[mi][ni], 0, 0, 0);
              acc[mi][ni] = __builtin_amdgcn_mfma_f32_16x16x32_bf16(ah[mi], bl[ni], acc[mi][ni], 0, 0, 0);
              acc[mi][ni] = __builtin_amdgcn_mfma_f32_16x16x32_bf16(al[mi], bh[ni], acc[mi][ni], 0, 0, 0);
            }
        }
      }
      // epilogue: C/D layout col = lane&15, row = 4*(lane>>4)+reg
      if (job.dbase < 0) {
        bf16* oh = ws + job.oh; bf16* ol = ws + job.ol;
#pragma unroll
        for (int mi = 0; mi < 4; ++mi)
#pragma unroll
          for (int ni = 0; ni < 4; ++ni) {
            const int cl = (wn << 6) + (ni << 4) + l15;
#pragma unroll
            for (int rg = 0; rg < 4; ++rg) {
              const int rl = (wm << 6) + (mi << 4) + (lk << 2) + rg;
              bf16 h, l; split1(acc[mi][ni][rg], h, l);
              oh[(size_t)(m0 + rl) * 1024 + n0 + cl] = h;
              ol[(size_t)(m0 + rl) * 1024 + n0 + cl] = l;
            }
          }
      } else {
        bf16* kb = ws + job.oh;
        const int d = job.dbase + my;           // tile row-block = G_j block j = my
#pragma unroll
        for (int mi = 0; mi < 4; ++mi)
#pragma unroll
          for (int ni = 0; ni < 4; ++ni) {
            const int cl = (wn << 6) + (ni << 4) + l15;
#pragma unroll
            for (int rg = 0; rg < 4; ++rg) {
              const int rl = (wm << 6) + (mi << 4) + (lk << 2) + rg;   // y index
              bf16 h, l; split1(acc[mi][ni][rg], h, l);
              kb[(size_t)rl * KTOT + (size_t)d * 128 + cl] = h;
            }
          }
      }
    }
    // ---- device-scope grid barrier (256 WGs, 1/CU, 32KB LDS: all co-resident) ----
    __syncthreads();
    if (tid == 0) {
      __hip_atomic_fetch_add(bar, 1, __ATOMIC_RELEASE, __HIP_MEMORY_SCOPE_AGENT);
      const int target = 256 * (lvl + 1);
      while (__hip_atomic_load(bar, __ATOMIC_ACQUIRE, __HIP_MEMORY_SCOPE_AGENT) < target)
        __builtin_amdgcn_s_sleep(8);
    }
    __syncthreads();
  }
}

// ---------- main conv: out(32768x128) += A_virt @ Kbt, split-K ----------
// Double-buffered LDS, counted vmcnt(8): next tile's global_load_lds fly during
// current tile's MFMA. barrier2 at loop tail protects the buffer being restaged.
__global__ __launch_bounds__(256) void conv_mfma(
    const bf16* __restrict__ Ubf, const bf16* __restrict__ Kbt, float* __restrict__ out)
{
  __shared__ __align__(16) bf16 As[2][128 * 64];
  __shared__ __align__(16) bf16 Bs[2][128 * 64];
  const int tid = threadIdx.x;
  const int t0 = blockIdx.x << 7;
  const int lane = tid & 63, wave = tid >> 6;
  const int wm = wave & 1, wn = wave >> 1;
  const int l15 = lane & 15, lk = lane >> 4;
  const int srow = tid >> 3, sc8 = (tid & 7) << 3;
  const int g8 = (((tid & 7) ^ (srow & 7)) << 3);
  const int ca0 = ((lk ^ (l15 & 7)) << 3);
  const int ca1 = (((4 + lk) ^ (l15 & 7)) << 3);
  const int ntot = KTOT / 64;                       // 226
  const int sb = (blockIdx.y * ntot) / SPLITK;
  const int se = ((blockIdx.y + 1) * ntot) / SPLITK;
  f32x4 acc[4][4] = {};

  auto stage = [&](int it, int buf) {
    const int kk0 = it << 6;
    const int d = kk0 >> 7, s0 = kk0 & 127;
    const bf16* srcA = Ubf + (size_t)(LTRUNC + t0 - d) * 128 + s0;
    const bf16* srcB = Kbt + kk0;
#pragma unroll
    for (int p = 0; p < 4; ++p) {
      const int row = (p << 5) + srow;
      gload16(srcA + (size_t)row * 128 + g8, &As[buf][row * 64 + sc8]);
      gload16(srcB + (size_t)row * KTOT + g8, &Bs[buf][row * 64 + sc8]);
    }
  };

  stage(sb, 0);                                     // prologue: 8 loads in flight
  int cur = 0;
  for (int it = sb; it < se; ++it) {
    if (it + 1 < se) {
      stage(it + 1, cur ^ 1);                       // +8 loads (other buffer)
      asm volatile("s_waitcnt vmcnt(8)" ::: "memory");   // oldest 8 (this tile) landed
    } else {
      asm volatile("s_waitcnt vmcnt(0)" ::: "memory");
    }
    __builtin_amdgcn_s_barrier();                   // all waves' portions landed
    __builtin_amdgcn_sched_barrier(0);
#pragma unroll
    for (int kh = 0; kh < 2; ++kh) {
      const int cb = kh ? ca1 : ca0;
      short8 a[4], b[4];
#pragma unroll
      for (int mi = 0; mi < 4; ++mi)
        a[mi] = *reinterpret_cast<const short8*>(&As[cur][((wm << 6) + (mi << 4) + l15) * 64 + cb]);
#pragma unroll
      for (int ni = 0; ni < 4; ++ni)
        b[ni] = *reinterpret_cast<const short8*>(&Bs[cur][((wn << 6) + (ni << 4) + l15) * 64 + cb]);
#pragma unroll
      for (int mi = 0; mi < 4; ++mi)
#pragma unroll
        for (int ni = 0; ni < 4; ++ni)
          acc[mi][ni] = __builtin_amdgcn_mfma_f32_16x16x32_bf16(a[mi], b[ni], acc[mi][ni], 0, 0, 0);
    }
    __builtin_amdgcn_sched_barrier(0);
    __builtin_amdgcn_s_barrier();                   // everyone done reading buf[cur]
    cur ^= 1;
  }
#pragma unroll
  for (int mi = 0; mi < 4; ++mi)
#pragma unroll
    for (int ni = 0; ni < 4; ++ni) {
      const int rcol = (wn << 6) + (ni << 4) + l15;
#pragma unroll
      for (int rg = 0; rg < 4; ++rg) {
        const int t = t0 + (wm << 6) + (mi << 4) + (lk << 2) + rg;
        atomicAdd(out + (size_t)t * 128 + rcol, acc[mi][ni][rg]);
      }
    }
}

extern "C" void kernel_launch(void* const* d_in, const int* in_sizes, int n_in,
                              void* d_out, int out_size, void* d_ws, size_t ws_size,
                              hipStream_t stream)
{
  const float* inp = (const float*)d_in[0];
  const float* Aw  = (const float*)d_in[1];
  const float* Bw  = (const float*)d_in[2];
  const float* Cw  = (const float*)d_in[3];
  const float* Dw  = (const float*)d_in[4];
  float* out = (float*)d_out;
  (void)in_sizes; (void)n_in; (void)out_size; (void)ws_size;

  bf16* W = (bf16*)d_ws;
  int* bar = (int*)((char*)d_ws + O_BAR_BYTES);

  // ---- pre-passes (independent, small) ----
  hipMemsetAsync(W + O_UBF, 0, (size_t)LTRUNC * 128 * 2, stream);       // Ubf pad rows
  ubuild<<<dim3(NSTEPS / 64, 2), 256, 0, stream>>>(inp, W + O_UBF);
  split_rm<<<1024, 256, 0, stream>>>(Aw, W + O_AHR, W + O_ALR);          // X0 = A rm
  split_cm<<<dim3(16, 16), 256, 0, stream>>>(Aw, W + O_AHC, W + O_ALC, 1024, 1024); // Y0 = A^T rm
  split_rm<<<128, 256, 0, stream>>>(Cw, W + O_GH, W + O_GL);             // G_0 = C
  split_cm<<<dim3(2, 16), 256, 0, stream>>>(Bw, W + O_RTH, W + O_RTL, 1024, 128);   // Rt_0 = B^T
  dinit<<<64, 256, 0, stream>>>(Dw, W + O_KBT);                          // K_0 = D
  hipMemsetAsync(bar, 0, 256, stream);                                   // grid-barrier counter

  // ---- entire 8-level precompute chain in one persistent dispatch ----
  chain_mega<<<256, 256, 0, stream>>>(W, bar);

  // ---- main truncated convolution ----
  hipMemsetAsync(out, 0, (size_t)NSTEPS * 128 * 4, stream);
  conv_mfma<<<dim3(NSTEPS / 128, SPLITK), 256, 0, stream>>>(W + O_UBF, W + O_KBT, out);
}